// Round 1
// baseline (112.257 us; speedup 1.0000x reference)
//
#include <hip/hip_runtime.h>
#include <hip/hip_bf16.h>

// Reference: for i in range(y): x = x + i  ==>  out = x + y*(y-1)/2
// x: float32 [8192,8192], y: python int (1-element int array on device).
// Pure streaming elementwise add -> memory-bound; float4 vectorized.

__global__ __launch_bounds__(256) void loop_add_kernel(
    const float* __restrict__ x,
    const int* __restrict__ y_ptr,
    float* __restrict__ out,
    long long n)
{
    const long long y = (long long)(*y_ptr);
    const float c = (float)(y * (y - 1) / 2);

    const long long n4 = n >> 2;  // number of float4 chunks
    const long long tid = (long long)blockIdx.x * blockDim.x + threadIdx.x;
    const long long stride = (long long)gridDim.x * blockDim.x;

    const float4* __restrict__ x4 = (const float4*)x;
    float4* __restrict__ o4 = (float4*)out;

    for (long long i = tid; i < n4; i += stride) {
        float4 v = x4[i];
        v.x += c; v.y += c; v.z += c; v.w += c;
        o4[i] = v;
    }

    // scalar tail (n % 4), handled by first few threads
    const long long tail_start = n4 << 2;
    for (long long i = tail_start + tid; i < n; i += stride) {
        out[i] = x[i] + c;
    }
}

extern "C" void kernel_launch(void* const* d_in, const int* in_sizes, int n_in,
                              void* d_out, int out_size, void* d_ws, size_t ws_size,
                              hipStream_t stream) {
    const float* x = (const float*)d_in[0];
    const int* y_ptr = (const int*)d_in[1];
    float* out = (float*)d_out;
    const long long n = (long long)out_size;

    const int block = 256;
    const int grid = 2048;  // grid-stride; ~8 blocks/CU worth of waves
    loop_add_kernel<<<grid, block, 0, stream>>>(x, y_ptr, out, n);
}